// Round 5
// baseline (108.495 us; speedup 1.0000x reference)
//
#include <hip/hip_runtime.h>

// MultiLinear: out[n,h] = sum_d x[n,d] * W[idx[n],d,h] + b[idx[n],h]
// N=2048, D=512, H=512, NH=16. fp32 in/out, bf16 MFMA internally.
//
// R5: R4's pair-loop preloaded 128 VGPRs of A-frags (+64 in-flight loads) ->
// spill/serialization at 2 blocks/CU; kernel est. ~38us despite ~6us of work.
// Now: (a) stream A per k-step (live set ~80 VGPR, launch_bounds(256,4)),
// (b) 1024 blocks via sample-split (4 blocks/CU, 16 waves/CU to hide L2/HBM
// latency; W staged 2x but L3-resident), (c) W->LDS staging uses packed b32
// writes (2 consecutive d per thread), 2-way bank overlap = free.

#define N_SAMPLES 2048
#define DIM       512
#define HDIM      512
#define N_HEADS   16
#define SH        16              // h-columns per block (one MFMA n-tile)
#define SG        2               // sample-split factor
#define BPITCH    520             // ushorts per LDS B row; 1040B=65*16: b128-aligned,
                                  // bank-group multiplicity 8 = conflict-free for b128

typedef __attribute__((ext_vector_type(8))) short bf16x8;
typedef __attribute__((ext_vector_type(4))) float floatx4;

__device__ inline unsigned short f2bf_rne(float f) {
    union { float f; unsigned u; } v; v.f = f;
    return (unsigned short)((v.u + 0x7FFFu + ((v.u >> 16) & 1u)) >> 16);
}
__device__ inline unsigned bfpack_rne(float lo, float hi) {   // bf16(lo) | bf16(hi)<<16
    return (unsigned)f2bf_rne(lo) | ((unsigned)f2bf_rne(hi) << 16);
}
// two fp32 -> packed bf16x2 by truncation (x path): one v_perm_b32
__device__ inline unsigned bf2_trunc(float lo, float hi) {
    return __builtin_amdgcn_perm(__float_as_uint(hi), __float_as_uint(lo), 0x07060302u);
}
__device__ inline bf16x8 pack_a(const float4 u0, const float4 u1) {
    union { bf16x8 v; unsigned u[4]; } r;
    r.u[0] = bf2_trunc(u0.x, u0.y);
    r.u[1] = bf2_trunc(u0.z, u0.w);
    r.u[2] = bf2_trunc(u1.x, u1.y);
    r.u[3] = bf2_trunc(u1.z, u1.w);
    return r.v;
}

__global__ __launch_bounds__(256, 4) void fused(
    const float* __restrict__ x,      // N x D fp32
    const int*   __restrict__ idx,    // N
    const float* __restrict__ w,      // NH x D x H fp32
    const float* __restrict__ bias,   // NH x H fp32
    float*       __restrict__ out)    // N x H fp32
{
    __shared__ unsigned short Bl[SH * BPITCH];   // 16.6 KB, [h][d] bf16, padded
    __shared__ int slist[N_SAMPLES];             // 8 KB (worst-case head size)
    __shared__ int wcnt[4];

    const int bid  = blockIdx.x;
    const int sg   = bid & (SG - 1);
    const int sid  = bid >> 1;                   // head*32 + stripe
    const int head = sid >> 5;
    const int h0   = (sid & 31) * SH;
    const int t    = threadIdx.x;
    const int wave = t >> 6;
    const int lane = t & 63;
    const int l16  = lane & 15;
    const int quad = lane >> 4;

    // ---- read idx chunk for ballot (loads issued early, used after staging) ----
    int myidx[8];
    #pragma unroll
    for (int c = 0; c < 8; ++c)
        myidx[c] = idx[(wave * 8 + c) * 64 + lane];

    // ---- stage W stripe: 512d x 16h fp32 -> bf16 LDS [h][d], b32 packed writes ----
    {
        const float* wg = w + (size_t)head * DIM * HDIM + h0;
        #pragma unroll
        for (int i = 0; i < 4; ++i) {
            const int flat = i * 256 + t;        // 0..1023: 256 d-pairs x 4 h-groups
            const int dp   = flat >> 2;          // d-pair 0..255
            const int hg   = (flat & 3) * 4;
            const float4 v0 = *(const float4*)(wg + (size_t)(2 * dp) * HDIM + hg);
            const float4 v1 = *(const float4*)(wg + (size_t)(2 * dp + 1) * HDIM + hg);
            *(unsigned*)&Bl[(hg + 0) * BPITCH + 2 * dp] = bfpack_rne(v0.x, v1.x);
            *(unsigned*)&Bl[(hg + 1) * BPITCH + 2 * dp] = bfpack_rne(v0.y, v1.y);
            *(unsigned*)&Bl[(hg + 2) * BPITCH + 2 * dp] = bfpack_rne(v0.z, v1.z);
            *(unsigned*)&Bl[(hg + 3) * BPITCH + 2 * dp] = bfpack_rne(v0.w, v1.w);
        }
    }

    // ---- ballot compaction of this head's samples (no atomics) ----
    unsigned long long masks[8];
    {
        int mycnt = 0;
        #pragma unroll
        for (int c = 0; c < 8; ++c) {
            masks[c] = __ballot(myidx[c] == head);
            mycnt += __popcll(masks[c]);
        }
        if (lane == 0) wcnt[wave] = mycnt;
    }
    __syncthreads();                             // wcnt visible
    int cnt = 0, base = 0;
    #pragma unroll
    for (int i = 0; i < 4; ++i) { if (i < wave) base += wcnt[i]; cnt += wcnt[i]; }
    {
        int pos = base;
        #pragma unroll
        for (int c = 0; c < 8; ++c) {
            const unsigned long long m = masks[c];
            if (m & (1ull << lane)) {
                const int rank = __popcll(m & ((1ull << lane) - 1ull));
                slist[pos + rank] = (wave * 8 + c) * 64 + lane;
            }
            pos += __popcll(m);
        }
    }
    __syncthreads();                             // slist + Bl visible

    const float bv = bias[head * HDIM + h0 + l16];

    // ---- compute: pair of 16-sample tiles per wave-iteration, streamed A ----
    for (int p = wave + 4 * sg; p * 32 < cnt; p += 4 * SG) {
        const int t0 = 2 * p, t1 = 2 * p + 1;
        const int mg0 = t0 * 16 + l16;
        const int mg1 = t1 * 16 + l16;
        const int r0 = slist[mg0 < cnt ? mg0 : cnt - 1];
        const int r1 = slist[mg1 < cnt ? mg1 : cnt - 1];
        const float* xp0 = x + (size_t)r0 * DIM + quad * 8;
        const float* xp1 = x + (size_t)r1 * DIM + quad * 8;

        floatx4 acc0 = {0.f, 0.f, 0.f, 0.f};
        floatx4 acc1 = {0.f, 0.f, 0.f, 0.f};
        #pragma unroll
        for (int ks = 0; ks < 16; ++ks) {
            const float4 u0 = *(const float4*)(xp0 + ks * 32);
            const float4 u1 = *(const float4*)(xp0 + ks * 32 + 4);
            const float4 v0 = *(const float4*)(xp1 + ks * 32);
            const float4 v1 = *(const float4*)(xp1 + ks * 32 + 4);
            const bf16x8 bfrag = *(const bf16x8*)&Bl[l16 * BPITCH + ks * 32 + quad * 8];
            acc0 = __builtin_amdgcn_mfma_f32_16x16x32_bf16(pack_a(u0, u1), bfrag, acc0, 0, 0, 0);
            acc1 = __builtin_amdgcn_mfma_f32_16x16x32_bf16(pack_a(v0, v1), bfrag, acc1, 0, 0, 0);
        }

        // C[m][n]: n = l16, m = quad*4 + r
        #pragma unroll
        for (int r = 0; r < 4; ++r) {
            const int m0 = t0 * 16 + quad * 4 + r;
            if (m0 < cnt) out[(size_t)slist[m0] * HDIM + h0 + l16] = acc0[r] + bv;
            const int m1 = t1 * 16 + quad * 4 + r;
            if (m1 < cnt) out[(size_t)slist[m1] * HDIM + h0 + l16] = acc1[r] + bv;
        }
    }
}

extern "C" void kernel_launch(void* const* d_in, const int* in_sizes, int n_in,
                              void* d_out, int out_size, void* d_ws, size_t ws_size,
                              hipStream_t stream) {
    const float* x   = (const float*)d_in[0];
    const int*   idx = (const int*)  d_in[1];
    const float* w   = (const float*)d_in[2];
    const float* b   = (const float*)d_in[3];
    float*       out = (float*)d_out;

    fused<<<N_HEADS * (HDIM / SH) * SG, 256, 0, stream>>>(x, idx, w, b, out);
}

// Round 6
// 87.750 us; speedup vs baseline: 1.2364x; 1.2364x over previous
//
#include <hip/hip_runtime.h>

// MultiLinear: out[n,h] = sum_d x[n,d] * W[idx[n],d,h] + b[idx[n],h]
// N=2048, D=512, H=512, NH=16. fp32 in/out, bf16 MFMA internally.
//
// R6: R5 was an outstanding-requests-bound gather: VGPR=60 -> ~4 loads in
// flight/wave, 128MB logical x-traffic (32x re-read), half the grid idle from
// a broken SG split. Now: (a) x pre-converted to bf16 (1 load-inst per A-frag,
// half the bytes), (b) SH=32 halves x re-reads (16 stripes), (c) SG=2 with
// correct m-interleave (m=2j+sg), (d) wave preloads 16 independent A-frag
// loads (forced deep batch) feeding TWO n-tile MFMA chains per A-load set.

#define N_SAMPLES 2048
#define DIM       512
#define HDIM      512
#define N_HEADS   16
#define SH        32              // h-columns per block = 2 MFMA n-tiles
#define SG        2               // sample-split (m-tile interleave)
#define BPITCH    520             // ushorts per LDS B row: 1040B; row stride
                                  // 260 dw == 4 mod 32 -> b128 reads conflict-free

typedef __attribute__((ext_vector_type(8))) short bf16x8;
typedef __attribute__((ext_vector_type(4))) float floatx4;

__device__ inline unsigned short f2bf_rne(float f) {
    union { float f; unsigned u; } v; v.f = f;
    return (unsigned short)((v.u + 0x7FFFu + ((v.u >> 16) & 1u)) >> 16);
}
__device__ inline unsigned bfpack_rne(float lo, float hi) {   // bf16(lo)|bf16(hi)<<16
    return (unsigned)f2bf_rne(lo) | ((unsigned)f2bf_rne(hi) << 16);
}

// ---- prep: x (fp32) -> xb (bf16, RNE), 8 elems/thread, 16B stores ----
__global__ __launch_bounds__(256) void xconv(const float* __restrict__ x,
                                             unsigned* __restrict__ xb) {
    const int i = blockIdx.x * 256 + threadIdx.x;      // 0..131071
    const float4 v0 = *(const float4*)(x + i * 8);
    const float4 v1 = *(const float4*)(x + i * 8 + 4);
    uint4 o;
    o.x = bfpack_rne(v0.x, v0.y);
    o.y = bfpack_rne(v0.z, v0.w);
    o.z = bfpack_rne(v1.x, v1.y);
    o.w = bfpack_rne(v1.z, v1.w);
    *(uint4*)(xb + i * 4) = o;
}

__global__ __launch_bounds__(256, 2) void fused(
    const unsigned short* __restrict__ xb,   // N x D bf16
    const int*   __restrict__ idx,           // N
    const float* __restrict__ w,             // NH x D x H fp32
    const float* __restrict__ bias,          // NH x H fp32
    float*       __restrict__ out)           // N x H fp32
{
    __shared__ unsigned short Bl[SH * BPITCH];   // 33.3 KB, [h][d] bf16, padded
    __shared__ int slist[N_SAMPLES];             // 8 KB (worst-case head size)
    __shared__ int wcnt[4];

    const int bid  = blockIdx.x;
    const int sg   = bid & (SG - 1);
    const int sid  = bid >> 1;                   // head*16 + stripe
    const int head = sid >> 4;
    const int h0   = (sid & 15) * SH;
    const int t    = threadIdx.x;
    const int wave = t >> 6;
    const int lane = t & 63;
    const int l16  = lane & 15;
    const int quad = lane >> 4;

    // ---- idx loads issued early (used after W staging) ----
    int myidx[8];
    #pragma unroll
    for (int c = 0; c < 8; ++c)
        myidx[c] = idx[(wave * 8 + c) * 64 + lane];

    // ---- stage W stripe: 512d x 32h fp32 -> bf16 LDS [h][d] ----
    // task = (dquad 0..127) x (hgroup 0..7); per task 4 coalesced float4 loads,
    // 4x uint2 (8B) LDS writes of packed bf16 pairs.
    {
        const float* wg = w + (size_t)head * DIM * HDIM + h0;
        #pragma unroll
        for (int i = 0; i < 4; ++i) {
            const int task = i * 256 + t;        // 0..1023
            const int dq   = task & 127;
            const int hg   = task >> 7;          // 0..7
            const int d0   = dq * 4;
            const int hh0  = hg * 4;
            const float4 q0 = *(const float4*)(wg + (size_t)(d0 + 0) * HDIM + hh0);
            const float4 q1 = *(const float4*)(wg + (size_t)(d0 + 1) * HDIM + hh0);
            const float4 q2 = *(const float4*)(wg + (size_t)(d0 + 2) * HDIM + hh0);
            const float4 q3 = *(const float4*)(wg + (size_t)(d0 + 3) * HDIM + hh0);
            uint2 p;
            p.x = bfpack_rne(q0.x, q1.x); p.y = bfpack_rne(q2.x, q3.x);
            *(uint2*)&Bl[(hh0 + 0) * BPITCH + d0] = p;
            p.x = bfpack_rne(q0.y, q1.y); p.y = bfpack_rne(q2.y, q3.y);
            *(uint2*)&Bl[(hh0 + 1) * BPITCH + d0] = p;
            p.x = bfpack_rne(q0.z, q1.z); p.y = bfpack_rne(q2.z, q3.z);
            *(uint2*)&Bl[(hh0 + 2) * BPITCH + d0] = p;
            p.x = bfpack_rne(q0.w, q1.w); p.y = bfpack_rne(q2.w, q3.w);
            *(uint2*)&Bl[(hh0 + 3) * BPITCH + d0] = p;
        }
    }

    // ---- ballot compaction of this head's samples (no atomics) ----
    unsigned long long masks[8];
    {
        int mycnt = 0;
        #pragma unroll
        for (int c = 0; c < 8; ++c) {
            masks[c] = __ballot(myidx[c] == head);
            mycnt += __popcll(masks[c]);
        }
        if (lane == 0) wcnt[wave] = mycnt;
    }
    __syncthreads();                             // wcnt visible
    int cnt = 0, base = 0;
    #pragma unroll
    for (int i = 0; i < 4; ++i) { if (i < wave) base += wcnt[i]; cnt += wcnt[i]; }
    {
        int pos = base;
        #pragma unroll
        for (int c = 0; c < 8; ++c) {
            const unsigned long long m = masks[c];
            if (m & (1ull << lane)) {
                const int rank = __popcll(m & ((1ull << lane) - 1ull));
                slist[pos + rank] = (wave * 8 + c) * 64 + lane;
            }
            pos += __popcll(m);
        }
    }
    __syncthreads();                             // slist + Bl visible

    const int   mt  = (cnt + 15) >> 4;           // m-tiles for this head
    const float bv0 = bias[head * HDIM + h0 + l16];
    const float bv1 = bias[head * HDIM + h0 + 16 + l16];

    // ---- compute: m = 2j+sg, j strided over waves; A preloaded (16 deep) ----
    for (int j = wave; 2 * j + sg < mt; j += 4) {
        const int m  = 2 * j + sg;
        const int mg = m * 16 + l16;
        const int row = slist[mg < cnt ? mg : cnt - 1];
        const unsigned short* ap = xb + (size_t)row * DIM + quad * 8;

        bf16x8 a[16];                            // 16 independent 16B loads in flight
        #pragma unroll
        for (int ks = 0; ks < 16; ++ks)
            a[ks] = *(const bf16x8*)(ap + ks * 32);

        floatx4 acc0 = {0.f, 0.f, 0.f, 0.f};
        floatx4 acc1 = {0.f, 0.f, 0.f, 0.f};
        #pragma unroll
        for (int ks = 0; ks < 16; ++ks) {
            const bf16x8 b0 = *(const bf16x8*)&Bl[l16 * BPITCH + ks * 32 + quad * 8];
            const bf16x8 b1 = *(const bf16x8*)&Bl[(16 + l16) * BPITCH + ks * 32 + quad * 8];
            acc0 = __builtin_amdgcn_mfma_f32_16x16x32_bf16(a[ks], b0, acc0, 0, 0, 0);
            acc1 = __builtin_amdgcn_mfma_f32_16x16x32_bf16(a[ks], b1, acc1, 0, 0, 0);
        }

        // C[m][n]: n = l16 (h), sample row = quad*4 + r
        #pragma unroll
        for (int r = 0; r < 4; ++r) {
            const int mm = m * 16 + quad * 4 + r;
            if (mm < cnt) {
                const int rg = slist[mm];
                out[(size_t)rg * HDIM + h0 + l16]      = acc0[r] + bv0;
                out[(size_t)rg * HDIM + h0 + 16 + l16] = acc1[r] + bv1;
            }
        }
    }
}

extern "C" void kernel_launch(void* const* d_in, const int* in_sizes, int n_in,
                              void* d_out, int out_size, void* d_ws, size_t ws_size,
                              hipStream_t stream) {
    const float* x   = (const float*)d_in[0];
    const int*   idx = (const int*)  d_in[1];
    const float* w   = (const float*)d_in[2];
    const float* b   = (const float*)d_in[3];
    float*       out = (float*)d_out;

    unsigned* xb = (unsigned*)d_ws;              // 2 MB bf16 x

    xconv<<<512, 256, 0, stream>>>(x, xb);
    fused<<<N_HEADS * 16 * SG, 256, 0, stream>>>((const unsigned short*)xb, idx, w, b, out);
}

// Round 7
// 87.319 us; speedup vs baseline: 1.2425x; 1.0049x over previous
//
#include <hip/hip_runtime.h>

// MultiLinear: out[n,h] = sum_d x[n,d] * W[idx[n],d,h] + b[idx[n],h]
// N=2048, D=512, H=512, NH=16. fp32 in/out, bf16 MFMA internally.
//
// R7: fixed floor measured ~65us (ws-poison 43.3 + restore/gaps ~21); R6's
// controllable part ~22.7us vs ~6us model. Fixes: (a) SG=1 — W staged once
// (16MB total, was 32), grid 256 = 1 block/CU, each wave owns ~2 m-tiles;
// (b) staging loads row-contiguous (8 lanes x 128B segments; 16 cache lines
// per inst, was 64) and all 16 float4 issued into regs before converting;
// (c) software-pipelined m-loop (prefetch next A-tile set during MFMA);
// (d) slist as ushort (LDS 37.4KB).

#define N_SAMPLES 2048
#define DIM       512
#define HDIM      512
#define N_HEADS   16
#define SH        32              // h-columns per block = 2 MFMA n-tiles
#define BPITCH    520             // ushorts per Bl row: 1040B, 16B-aligned rows;
                                  // b128 compute reads at conflict-free baseline

typedef __attribute__((ext_vector_type(8))) short bf16x8;
typedef __attribute__((ext_vector_type(4))) float floatx4;

__device__ inline unsigned short f2bf_rne(float f) {
    union { float f; unsigned u; } v; v.f = f;
    return (unsigned short)((v.u + 0x7FFFu + ((v.u >> 16) & 1u)) >> 16);
}
__device__ inline unsigned bfpack_rne(float lo, float hi) {   // bf16(lo)|bf16(hi)<<16
    return (unsigned)f2bf_rne(lo) | ((unsigned)f2bf_rne(hi) << 16);
}

// ---- prep: x (fp32) -> xb (bf16 RNE), 8 elems/thread, 16B stores ----
__global__ __launch_bounds__(256) void xconv(const float* __restrict__ x,
                                             unsigned* __restrict__ xb) {
    const int i = blockIdx.x * 256 + threadIdx.x;      // 0..131071
    const float4 v0 = *(const float4*)(x + i * 8);
    const float4 v1 = *(const float4*)(x + i * 8 + 4);
    uint4 o;
    o.x = bfpack_rne(v0.x, v0.y);
    o.y = bfpack_rne(v0.z, v0.w);
    o.z = bfpack_rne(v1.x, v1.y);
    o.w = bfpack_rne(v1.z, v1.w);
    *(uint4*)(xb + i * 4) = o;
}

__global__ __launch_bounds__(256, 2) void fused(
    const unsigned short* __restrict__ xb,   // N x D bf16
    const int*   __restrict__ idx,           // N
    const float* __restrict__ w,             // NH x D x H fp32
    const float* __restrict__ bias,          // NH x H fp32
    float*       __restrict__ out)           // N x H fp32
{
    __shared__ unsigned short Bl[SH * BPITCH];      // 33.3 KB, [h][d] bf16
    __shared__ unsigned short slist[N_SAMPLES];     // 4 KB
    __shared__ int wcnt[4];

    const int bid  = blockIdx.x;                    // 256 blocks = head x 16 stripes
    const int head = bid >> 4;
    const int h0   = (bid & 15) * SH;
    const int t    = threadIdx.x;
    const int wave = t >> 6;
    const int lane = t & 63;
    const int l16  = lane & 15;
    const int quad = lane >> 4;

    // ---- idx loads first (oldest in flight; ballot waits only on these) ----
    int myidx[8];
    #pragma unroll
    for (int c = 0; c < 8; ++c)
        myidx[c] = idx[(wave * 8 + c) * 64 + lane];

    // ---- issue ALL W loads into regs (row-contiguous: lanes 0..7 cover one
    //      128B d-row segment; 16 float4/thread = whole 512d x 32h stripe) ----
    const int hh = (t & 7) * 4;                     // 0..28
    const int dg = t >> 3;                          // 0..31, d-range [dg*16, +16)
    const float* wg = w + (size_t)head * DIM * HDIM + h0;
    float4 q[16];
    #pragma unroll
    for (int s = 0; s < 16; ++s)
        q[s] = *(const float4*)(wg + (size_t)(dg * 16 + s) * HDIM + hh);

    // ---- ballot compaction (overlaps W-load flight; waits only idx) ----
    unsigned long long masks[8];
    {
        int mycnt = 0;
        #pragma unroll
        for (int c = 0; c < 8; ++c) {
            masks[c] = __ballot(myidx[c] == head);
            mycnt += __popcll(masks[c]);
        }
        if (lane == 0) wcnt[wave] = mycnt;
    }
    __syncthreads();                                // wcnt visible
    int cnt = 0, base = 0;
    #pragma unroll
    for (int i = 0; i < 4; ++i) { if (i < wave) base += wcnt[i]; cnt += wcnt[i]; }
    {
        int pos = base;
        #pragma unroll
        for (int c = 0; c < 8; ++c) {
            const unsigned long long m = masks[c];
            if (m & (1ull << lane)) {
                const int rank = __popcll(m & ((1ull << lane) - 1ull));
                slist[pos + rank] = (unsigned short)((wave * 8 + c) * 64 + lane);
            }
            pos += __popcll(m);
        }
    }

    // ---- convert staged W and write Bl[h][d] (packed d-pairs, b32 writes) ----
    #pragma unroll
    for (int p = 0; p < 8; ++p) {
        const int d = dg * 16 + 2 * p;
        const float4 qa = q[2 * p], qb = q[2 * p + 1];
        *(unsigned*)&Bl[(hh + 0) * BPITCH + d] = bfpack_rne(qa.x, qb.x);
        *(unsigned*)&Bl[(hh + 1) * BPITCH + d] = bfpack_rne(qa.y, qb.y);
        *(unsigned*)&Bl[(hh + 2) * BPITCH + d] = bfpack_rne(qa.z, qb.z);
        *(unsigned*)&Bl[(hh + 3) * BPITCH + d] = bfpack_rne(qa.w, qb.w);
    }
    __syncthreads();                                // Bl + slist visible

    const int   mt  = (cnt + 15) >> 4;              // m-tiles for this head
    const float bv0 = bias[head * HDIM + h0 + l16];
    const float bv1 = bias[head * HDIM + h0 + 16 + l16];

    // ---- software-pipelined m-loop: wave owns m-tiles j = wave, wave+4, ... ----
    int j = wave;
    bf16x8 a[16];
    if (j < mt) {
        const int mg  = j * 16 + l16;
        const int row = slist[mg < cnt ? mg : cnt - 1];
        const unsigned short* ap = xb + (size_t)row * DIM + quad * 8;
        #pragma unroll
        for (int ks = 0; ks < 16; ++ks) a[ks] = *(const bf16x8*)(ap + ks * 32);
    }
    for (; j < mt; j += 4) {
        bf16x8 an[16];
        const int jn = j + 4;
        if (jn < mt) {                              // prefetch next tile's A
            const int mg  = jn * 16 + l16;
            const int row = slist[mg < cnt ? mg : cnt - 1];
            const unsigned short* ap = xb + (size_t)row * DIM + quad * 8;
            #pragma unroll
            for (int ks = 0; ks < 16; ++ks) an[ks] = *(const bf16x8*)(ap + ks * 32);
        }

        floatx4 acc0 = {0.f, 0.f, 0.f, 0.f};
        floatx4 acc1 = {0.f, 0.f, 0.f, 0.f};
        #pragma unroll
        for (int ks = 0; ks < 16; ++ks) {
            const bf16x8 b0 = *(const bf16x8*)&Bl[l16 * BPITCH + ks * 32 + quad * 8];
            const bf16x8 b1 = *(const bf16x8*)&Bl[(16 + l16) * BPITCH + ks * 32 + quad * 8];
            acc0 = __builtin_amdgcn_mfma_f32_16x16x32_bf16(a[ks], b0, acc0, 0, 0, 0);
            acc1 = __builtin_amdgcn_mfma_f32_16x16x32_bf16(a[ks], b1, acc1, 0, 0, 0);
        }

        // C[m][n]: n = l16 (h), sample row = quad*4 + r; 64B-contiguous stores
        #pragma unroll
        for (int r = 0; r < 4; ++r) {
            const int mm = j * 16 + quad * 4 + r;
            if (mm < cnt) {
                const int rg = slist[mm];
                out[(size_t)rg * HDIM + h0 + l16]      = acc0[r] + bv0;
                out[(size_t)rg * HDIM + h0 + 16 + l16] = acc1[r] + bv1;
            }
        }

        #pragma unroll
        for (int ks = 0; ks < 16; ++ks) a[ks] = an[ks];
    }
}

extern "C" void kernel_launch(void* const* d_in, const int* in_sizes, int n_in,
                              void* d_out, int out_size, void* d_ws, size_t ws_size,
                              hipStream_t stream) {
    const float* x   = (const float*)d_in[0];
    const int*   idx = (const int*)  d_in[1];
    const float* w   = (const float*)d_in[2];
    const float* b   = (const float*)d_in[3];
    float*       out = (float*)d_out;

    unsigned* xb = (unsigned*)d_ws;                 // 2 MB bf16 x

    xconv<<<512, 256, 0, stream>>>(x, xb);
    fused<<<N_HEADS * (HDIM / SH), 256, 0, stream>>>((const unsigned short*)xb, idx, w, b, out);
}